// Round 6
// baseline (29745.020 us; speedup 1.0000x reference)
//
#include <hip/hip_runtime.h>
#include <math.h>

// Problem constants
#define TT 2048
#define NBLK 32
#define NTH 512

// d_out layout (floats): pred | attw | q_gru_n | dec_gru_n | query_n
#define OUT_ATTW   (2048*64*64)            // 8388608
#define OUT_QGRU   (OUT_ATTW + 2048*8*64)  // 9437184
#define OUT_DECGRU (OUT_QGRU + 256)        // 9437440
#define OUT_QN     (OUT_DECGRU + 256)      // 9437696

// d_ws layout (bytes)
#define WSO_MB1    0                               // ulong[2][512]  = 8192
#define WSO_HIDACC 8192                            // ulong[4][256]  = 8192
#define WSO_QACC   16384                           // ulong[4][512]  = 16384
#define WSO_ZEND   32768
#define WSO_GIFIX  32768                           // float[2048][768]
#define WSO_HIDFIX (WSO_GIFIX + 2048*768*4)        // float[2048][256]
#define WSO_QHWT   (WSO_HIDFIX + 2048*256*4)       // float[832][256]
#define WSO_W2T    (WSO_QHWT + 832*256*4)          // float[256][64]
#define WSO_DAVA   (WSO_W2T + 256*64*4)            // float[2048][512]
#define WSO_DECH   (WSO_DAVA + 2048*512*4)         // float[2048][256]
#define WSO_FEAT   (WSO_DECH + 2048*256*4)         // float[2048][832]
#define WSO_SBUF   (WSO_FEAT + 2048*832*4)         // float[2048][256]

#define PAYMASK ((1ULL<<56)-1)

__device__ __forceinline__ float warp_sum(float v) {
#pragma unroll
  for (int o = 32; o > 0; o >>= 1) v += __shfl_down(v, o, 64);
  return v;
}
__device__ __forceinline__ float warp_max(float v) {
#pragma unroll
  for (int o = 32; o > 0; o >>= 1) v = fmaxf(v, __shfl_down(v, o, 64));
  return v;
}
__device__ __forceinline__ float sigf(float x) { return 1.f / (1.f + __expf(-x)); }
__device__ __forceinline__ float dot4(float4 a, float4 b) {
  return a.x*b.x + a.y*b.y + a.z*b.z + a.w*b.w;
}
__device__ __forceinline__ unsigned long long aload64(const unsigned long long* p) {
  return __hip_atomic_load(p, __ATOMIC_RELAXED, __HIP_MEMORY_SCOPE_AGENT);
}
__device__ __forceinline__ void astore64(unsigned long long* p, unsigned long long v) {
  __hip_atomic_store(p, v, __ATOMIC_RELAXED, __HIP_MEMORY_SCOPE_AGENT);
}
__device__ __forceinline__ unsigned long long mbpack(float f, unsigned tag) {
  return ((unsigned long long)tag << 32) | (unsigned long long)__float_as_uint(f);
}
__device__ __forceinline__ float mbpoll(const unsigned long long* p, unsigned tag) {
  unsigned long long v = aload64(p);
  while ((unsigned)(v >> 32) != tag) {
    __builtin_amdgcn_s_sleep(1);
    v = aload64(p);
  }
  return __uint_as_float((unsigned)v);
}
// count-carrying fixed-point reduce: one u64 fetch_add per contribution;
// (u>>56)==32 is completion AND the payload is the finished sum.
__device__ __forceinline__ unsigned long long rpack(float v) {
  long long f = (long long)((double)v * 268435456.0);  // 2^28 scale, |v|<4096
  return (1ULL << 56) + (unsigned long long)(f + (1LL << 41));
}
__device__ __forceinline__ float runpack(unsigned long long u) {
  long long S = (long long)(u & PAYMASK) - (32LL << 41);
  return (float)((double)S * 3.725290298461914e-09);   // 2^-28
}
__device__ __forceinline__ unsigned long long cpoll(unsigned long long* p) {
  unsigned long long u = aload64(p);
  while ((u >> 56) != 32ULL) {
    __builtin_amdgcn_s_sleep(1);
    u = aload64(p);
  }
  return u;
}
__device__ __forceinline__ void radd(unsigned long long* p, float v) {
  __hip_atomic_fetch_add(p, rpack(v), __ATOMIC_RELAXED, __HIP_MEMORY_SCOPE_AGENT);
}

// ---------------- transposes: q_hid_w full, dec_out_w ----------------
__global__ void transpose_k(const float* __restrict__ qhw,  // [256,832]
                            const float* __restrict__ w2,   // [64,256]
                            float* __restrict__ qhwT,       // [832][256]
                            float* __restrict__ w2T) {      // [256,64]
  int g = blockIdx.x * 256 + threadIdx.x;
  if (g < 832 * 256) {
    int c = g >> 8, r = g & 255;
    qhwT[g] = qhw[r * 832 + c];
  } else {
    int e = g - 832 * 256;
    if (e < 16384) {
      int r = e >> 6, a = e & 63;
      w2T[e] = w2[a * 256 + r];
    }
  }
}

// ---------------- generic tiled GEMM: C[t][r] = bias[r] + sum_k X[t][k]*W[r][woff+k]
__global__ void __launch_bounds__(256) gemm64(
    const float* __restrict__ X, int ldx,
    const float* __restrict__ W, int ldw, int woff,
    const float* __restrict__ bias,
    float* __restrict__ C, int crows, int K) {
  __shared__ float Xs[64 * 65];
  __shared__ float Ws[64 * 65];
  int t0 = blockIdx.x * 64, r0 = blockIdx.y * 64;
  int tid = threadIdx.x;
  int u = tid & 15, v = tid >> 4;
  float acc[4][4];
#pragma unroll
  for (int i = 0; i < 4; i++)
#pragma unroll
    for (int j = 0; j < 4; j++) acc[i][j] = 0.f;

  for (int kc = 0; kc < K; kc += 64) {
    for (int idx = tid; idx < 4096; idx += 256) {
      int row = idx >> 6, col = idx & 63;
      Xs[row * 65 + col] = X[(size_t)(t0 + row) * ldx + kc + col];
      Ws[row * 65 + col] = W[(size_t)(r0 + row) * ldw + woff + kc + col];
    }
    __syncthreads();
#pragma unroll 8
    for (int k = 0; k < 64; k++) {
      float xs[4], ws[4];
#pragma unroll
      for (int i = 0; i < 4; i++) xs[i] = Xs[(v + 16 * i) * 65 + k];
#pragma unroll
      for (int j = 0; j < 4; j++) ws[j] = Ws[(u + 16 * j) * 65 + k];
#pragma unroll
      for (int i = 0; i < 4; i++)
#pragma unroll
        for (int j = 0; j < 4; j++) acc[i][j] += xs[i] * ws[j];
    }
    __syncthreads();
  }
#pragma unroll
  for (int i = 0; i < 4; i++)
#pragma unroll
    for (int j = 0; j < 4; j++) {
      int t = t0 + v + 16 * i, r = r0 + u + 16 * j;
      C[(size_t)t * crows + r] = acc[i][j] + bias[r];
    }
}

// -------- fused sequential kernel: 2 count-carrying reduces + 1 parallel mailbox
__global__ void __launch_bounds__(512) seq_kernel(
    const float* __restrict__ x_fix,    // [2048,64]
    const float* __restrict__ x_att,    // [2048,64,64]
    const float* __restrict__ w_ih,     // [768,1088]
    const float* __restrict__ w_hh,     // [768,256]
    const float* __restrict__ b_hh,     // [768]
    const float* __restrict__ qhwT,     // [832][256]
    const float* __restrict__ wq,       // [256,512]
    const float* __restrict__ dwih,     // [768,576]
    const float* __restrict__ dwhh,     // [768,256]
    const float* __restrict__ dbih,     // [768]
    const float* __restrict__ dbhh,     // [768]
    const float* __restrict__ gi_fix,   // [2048,768]
    const float* __restrict__ hid_fix,  // [2048,256]
    unsigned long long* __restrict__ mb1,     // [2][512] h2|dech mailbox
    unsigned long long* __restrict__ hidacc,  // [4][256]
    unsigned long long* __restrict__ qacc,    // [4][512]
    float* __restrict__ dava,           // [2048,512]
    float* __restrict__ dec_hist,       // [2048,256]
    float* __restrict__ out) {
  __shared__ float att_s[64 * 65];
  __shared__ float ring_s[16][512];
  __shared__ __align__(16) float avq_s[1024];  // [attv(512) | query(512)]
  __shared__ float qk_s[512];
  __shared__ __align__(16) float xcat_s[576];  // [fix | dec_att_a]
  __shared__ float hidown_s[8];
  __shared__ float h2own_s[8];
  __shared__ __align__(16) float h_s[256];
  __shared__ __align__(16) float dech_s[256];
  __shared__ float g_s[4][8];
  __shared__ float dg_s[4][8];

  const int tid = threadIdx.x;
  const int bid = blockIdx.x;
  const int lane = tid & 63, wv = tid >> 6;

  int qrows[3];
#pragma unroll
  for (int k = 0; k < 3; k++) {
    int m = wv * 3 + k;
    qrows[k] = ((m >> 3) * 256) + bid * 8 + (m & 7);
  }
  float acch_q[3] = {0.f, 0.f, 0.f};  // carried w_hh@h2(t-1) per-lane partials

  // init
  for (int i = tid; i < 1024; i += NTH) avq_s[i] = (i >= 512) ? 1.f : 0.f;
  if (tid < 256) { h_s[tid] = 0.f; dech_s[tid] = 0.f; }
  {
    const float4* g4 = (const float4*)x_att;
    float4 a = g4[tid * 2], b = g4[tid * 2 + 1];
    int row = tid >> 3, c0 = (tid & 7) * 8;
    float* d = &att_s[row * 65 + c0];
    d[0]=a.x; d[1]=a.y; d[2]=a.z; d[3]=a.w; d[4]=b.x; d[5]=b.y; d[6]=b.z; d[7]=b.w;
  }
  if (tid < 64) xcat_s[tid] = x_fix[tid];
  __syncthreads();

  for (int t = 0; t < TT; ++t) {
    const int HB = t & 3;
    const int QB = (t + 1) & 3;
    // ---- A: prefetch + attention(t) ----
    float4 pfa, pfb;
    float fixpf = 0.f;
    {
      int tn = (t + 1 < TT) ? t + 1 : t;
      const float4* g4 = (const float4*)(x_att + (size_t)tn * 4096);
      pfa = g4[tid * 2];
      pfb = g4[tid * 2 + 1];
      if (tid >= 448) fixpf = x_fix[tn * 64 + (tid - 448)];
    }
    {
      float acc = 0.f;
#pragma unroll 16
      for (int a = 0; a < 64; a++)
        acc += avq_s[512 + wv * 64 + a] * att_s[lane * 65 + a];
      acc *= 0.125f;
      float m = __shfl(warp_max(acc), 0, 64);
      float e = __expf(acc - m);
      float s = __shfl(warp_sum(e), 0, 64);
      qk_s[wv * 64 + lane] = e / s;
    }
    __syncthreads();  // qk published
    {
      float av = 0.f;
#pragma unroll 8
      for (int n = 0; n < 64; n++) av += qk_s[wv * 64 + n] * att_s[n * 65 + lane];
      avq_s[wv * 64 + lane] = av;
      if (t == 0) xcat_s[64 + wv * 64 + lane] = av;  // dec_att_a(0) == attv(0)
    }
    __syncthreads();  // S1: attv (+xcat at t=0) published
    // ---- B: q-gi dots + q-gate combine (gh part carried from prev G) ----
    {
      float accg[3] = {0.f, 0.f, 0.f};
      const float4* in4 = (const float4*)avq_s;
#pragma unroll
      for (int c0 = 0; c0 < 4; c0++) {
        int c = lane + 64 * c0;
        float4 v = in4[c];
#pragma unroll
        for (int k = 0; k < 3; k++) {
          const float4* W = (const float4*)(w_ih + (size_t)qrows[k] * 1088 + 64);
          accg[k] += dot4(W[c], v);
        }
      }
#pragma unroll
      for (int k = 0; k < 3; k++) {
        int m = wv * 3 + k;
        int gate = m >> 3, idx = m & 7;
        if (gate < 2) {
          float s = warp_sum(accg[k] + acch_q[k]);
          if (lane == 0)
            g_s[gate][idx] = s + gi_fix[(size_t)t * 768 + qrows[k]] + b_hh[qrows[k]];
        } else {
          float sg = warp_sum(accg[k]);
          float sh = warp_sum(acch_q[k]);
          if (lane == 0) {
            g_s[2][idx] = sg + gi_fix[(size_t)t * 768 + qrows[k]];
            g_s[3][idx] = sh + b_hh[qrows[k]];
          }
        }
      }
    }
    if (t == 0) {  // dec gates(0) inline (acch = 0, biases still added)
      float accg[3] = {0.f, 0.f, 0.f};
      const float4* x4 = (const float4*)xcat_s;
#pragma unroll
      for (int c0 = 0; c0 < 3; c0++) {
        int c = lane + 64 * c0;
        if (c < 144) {
          float4 v = x4[c];
#pragma unroll
          for (int k = 0; k < 3; k++) {
            const float4* W = (const float4*)(dwih + (size_t)qrows[k] * 576);
            accg[k] += dot4(W[c], v);
          }
        }
      }
#pragma unroll
      for (int k = 0; k < 3; k++) {
        int m = wv * 3 + k;
        int gate = m >> 3, idx = m & 7;
        if (gate < 2) {
          float s = warp_sum(accg[k]);
          if (lane == 0) dg_s[gate][idx] = s + dbih[qrows[k]] + dbhh[qrows[k]];
        } else {
          float sg = warp_sum(accg[k]);
          if (lane == 0) {
            dg_s[2][idx] = sg + dbih[qrows[k]];
            dg_s[3][idx] = dbhh[qrows[k]];
          }
        }
      }
    }
    __syncthreads();  // S2: g_s (and dg_s at t=0) published
    // ---- C: combine + E1 store + outputs + ring + tile(t+1) deposit ----
    if (tid < 8) {
      float r = sigf(g_s[0][tid]), z = sigf(g_s[1][tid]);
      float nn = tanhf(g_s[2][tid] + r * g_s[3][tid]);
      float h2 = (1.f - z) * nn + z * h_s[bid * 8 + tid];
      h2own_s[tid] = h2;
      astore64(&mb1[(size_t)(t & 1) * 512 + bid * 16 + tid],
               mbpack(h2, (unsigned)(t + 1)));
    } else if (tid < 16) {
      int i = tid - 8;
      float r = sigf(dg_s[0][i]), z = sigf(dg_s[1][i]);
      float nn = tanhf(dg_s[2][i] + r * dg_s[3][i]);
      float d2 = (1.f - z) * nn + z * dech_s[bid * 8 + i];
      astore64(&mb1[(size_t)(t & 1) * 512 + bid * 16 + tid],
               mbpack(d2, (unsigned)(t + 1)));
      dec_hist[(size_t)t * 256 + bid * 8 + i] = d2;
    } else if (tid < 32) {
      int i = tid - 16;
      out[OUT_ATTW + (size_t)t * 512 + bid * 16 + i] = qk_s[bid * 16 + i];
    } else if (tid < 48) {
      int i = tid - 32;
      dava[(size_t)t * 512 + bid * 16 + i] = xcat_s[64 + bid * 16 + i];
    }
    ring_s[t & 15][tid] = qk_s[tid];
    {
      int row = tid >> 3, c0 = (tid & 7) * 8;
      float* d = &att_s[row * 65 + c0];
      d[0]=pfa.x; d[1]=pfa.y; d[2]=pfa.z; d[3]=pfa.w;
      d[4]=pfb.x; d[5]=pfb.y; d[6]=pfb.z; d[7]=pfb.w;
    }
    __syncthreads();  // S3: h2own, ring(t), tile(t+1) published
    // ---- D: fire hid-pre contributions + deferred qacc zero ----
    if (tid < 256) {
      float c = 0.f;
      const float* Wh = qhwT + (size_t)(bid * 8) * 256 + tid;
#pragma unroll
      for (int k = 0; k < 8; k++) c += Wh[k * 256] * h2own_s[k];
      const float* Wa = qhwT + (size_t)(320 + bid * 16) * 256 + tid;
#pragma unroll
      for (int k = 0; k < 16; k++) c += Wa[k * 256] * avq_s[bid * 16 + k];
      radd(&hidacc[(size_t)HB * 256 + tid], c);
    }
    if (t >= 1) astore64(&qacc[(size_t)((t - 1) & 3) * 512 + tid], 0ULL);
    // ---- E: owners poll hid slots; others compute dec_att_a(t+1)+fix(t+1) ----
    if (tid < 8) {
      unsigned long long* slot = &hidacc[(size_t)HB * 256 + bid * 8 + tid];
      unsigned long long u = cpoll(slot);
      astore64(slot, 0ULL);  // owner-zero (only owner reads these)
      hidown_s[tid] =
          fmaxf(runpack(u) + hid_fix[(size_t)t * 256 + bid * 8 + tid], 0.f);
    } else {
      int jj = tid - 8;
      int slot_t1 = (t + 1 >= 16) ? ((t + 1) & 15) : 0;
      const float* rg = ring_s[slot_t1];
      {
        int h = jj >> 6, a = jj & 63;
        float dv = 0.f;
#pragma unroll 8
        for (int n = 0; n < 64; n++) dv += rg[h * 64 + n] * att_s[n * 65 + a];
        xcat_s[64 + jj] = dv;
      }
      if (jj < 8) {
        int j2 = jj + 504, h = j2 >> 6, a = j2 & 63;
        float dv = 0.f;
#pragma unroll 8
        for (int n = 0; n < 64; n++) dv += rg[h * 64 + n] * att_s[n * 65 + a];
        xcat_s[64 + j2] = dv;
      }
      if (tid >= 448) xcat_s[tid - 448] = fixpf;
    }
    __syncthreads();  // S4: hidown + xcat(t+1) published
    // ---- F: fire query(t+1) contributions ----
    {
      float p = 0.f;
#pragma unroll
      for (int k = 0; k < 8; k++)
        p += hidown_s[k] * wq[(size_t)(bid * 8 + k) * 512 + tid];
      radd(&qacc[(size_t)QB * 512 + tid], p);
    }
    // ---- G: E1 poll (arrived during RTT1) + next-step gh/dec dots ----
    {
      float f = mbpoll(mb1 + (size_t)(t & 1) * 512 + tid, (unsigned)(t + 1));
      int b = tid >> 4, j = tid & 15;
      if (j < 8) h_s[b * 8 + j] = f;
      else dech_s[b * 8 + j - 8] = f;
    }
    __syncthreads();  // S5: h2(t)/dech(t) full
    {
      const float4* h4 = (const float4*)h_s;
      float4 vh = h4[lane];
#pragma unroll
      for (int k = 0; k < 3; k++) {
        const float4* Wh = (const float4*)(w_hh + (size_t)qrows[k] * 256);
        acch_q[k] = dot4(Wh[lane], vh);
      }
      float accg[3] = {0.f, 0.f, 0.f}, acch[3];
      const float4* x4 = (const float4*)xcat_s;
#pragma unroll
      for (int c0 = 0; c0 < 3; c0++) {
        int c = lane + 64 * c0;
        if (c < 144) {
          float4 v = x4[c];
#pragma unroll
          for (int k = 0; k < 3; k++) {
            const float4* W = (const float4*)(dwih + (size_t)qrows[k] * 576);
            accg[k] += dot4(W[c], v);
          }
        }
      }
      const float4* dh4 = (const float4*)dech_s;
      float4 vd = dh4[lane];
#pragma unroll
      for (int k = 0; k < 3; k++) {
        const float4* Wh = (const float4*)(dwhh + (size_t)qrows[k] * 256);
        acch[k] = dot4(Wh[lane], vd);
      }
#pragma unroll
      for (int k = 0; k < 3; k++) {
        int m = wv * 3 + k;
        int gate = m >> 3, idx = m & 7;
        if (gate < 2) {
          float s = warp_sum(accg[k] + acch[k]);
          if (lane == 0) dg_s[gate][idx] = s + dbih[qrows[k]] + dbhh[qrows[k]];
        } else {
          float sg = warp_sum(accg[k]);
          float sh = warp_sum(acch[k]);
          if (lane == 0) {
            dg_s[2][idx] = sg + dbih[qrows[k]];
            dg_s[3][idx] = sh + dbhh[qrows[k]];
          }
        }
      }
    }
    // ---- H: poll query(t+1) ----
    {
      unsigned long long u = cpoll(&qacc[(size_t)QB * 512 + tid]);
      avq_s[512 + tid] = runpack(u);
    }
    __syncthreads();  // S6
  }

  if (bid == 0) {
    if (tid < 256) {
      out[OUT_QGRU + tid] = h_s[tid];
      out[OUT_DECGRU + tid] = dech_s[tid];
    }
    out[OUT_QN + tid] = avq_s[512 + tid];
  }
}

// ---------------- feat assembly: [dec_h | x_fix | dec_att_a] ----------------
__global__ void featcopy(const float* __restrict__ dec_hist,
                         const float* __restrict__ x_fix,
                         const float* __restrict__ dava,
                         float* __restrict__ feat) {
  int t = blockIdx.x, tid = threadIdx.x;
  float* f = feat + (size_t)t * 832;
  f[tid] = dec_hist[(size_t)t * 256 + tid];
  if (tid < 64) f[256 + tid] = x_fix[t * 64 + tid];
  for (int i = tid; i < 512; i += 256) f[320 + i] = dava[(size_t)t * 512 + i];
}

// ---------------- final MLP ----------------
__global__ void __launch_bounds__(256) final_k(
    const float* __restrict__ x_att,
    const float* __restrict__ s,      // [2048,256] shared part incl. b1
    const float* __restrict__ w1,     // dec_hid_w [256,896]
    const float* __restrict__ w2T,    // [256,64]
    const float* __restrict__ b2,     // [64]
    float* __restrict__ pred) {
  __shared__ float att_s[4096];
  __shared__ float s_s[256];
  __shared__ float hid_s[32 * 256];
  int t = blockIdx.x, tid = threadIdx.x, lane = tid & 63, wv = tid >> 6;
  for (int i = tid; i < 4096; i += 256) att_s[i] = x_att[(size_t)t * 4096 + i];
  s_s[tid] = s[(size_t)t * 256 + tid];
  float4 w1v[16];
  const float4* W1a4 = (const float4*)(w1 + (size_t)tid * 896 + 832);
#pragma unroll
  for (int q = 0; q < 16; q++) w1v[q] = W1a4[q];
  float bb = b2[lane];
  __syncthreads();
  for (int ch = 0; ch < 2; ch++) {
    for (int nl = 0; nl < 32; nl++) {
      int n = ch * 32 + nl;
      const float4* a4 = (const float4*)(att_s + n * 64);
      float acc = s_s[tid];
#pragma unroll
      for (int q = 0; q < 16; q++) acc += dot4(w1v[q], a4[q]);
      hid_s[nl * 256 + tid] = fmaxf(acc, 0.f);
    }
    __syncthreads();
    float accb[8];
#pragma unroll
    for (int j = 0; j < 8; j++) accb[j] = bb;
    for (int r = 0; r < 256; r++) {
      float w = w2T[r * 64 + lane];
#pragma unroll
      for (int j = 0; j < 8; j++) accb[j] += w * hid_s[(wv * 8 + j) * 256 + r];
    }
#pragma unroll
    for (int j = 0; j < 8; j++) {
      int n = ch * 32 + wv * 8 + j;
      pred[(size_t)t * 4096 + n * 64 + lane] = fmaxf(accb[j], 0.f);
    }
    __syncthreads();
  }
}

extern "C" void kernel_launch(void* const* d_in, const int* in_sizes, int n_in,
                              void* d_out, int out_size, void* d_ws, size_t ws_size,
                              hipStream_t stream) {
  const float* x_fix = (const float*)d_in[0];
  const float* x_att = (const float*)d_in[1];
  const float* qwih = (const float*)d_in[3];
  const float* qwhh = (const float*)d_in[4];
  const float* qbih = (const float*)d_in[5];
  const float* qbhh = (const float*)d_in[6];
  const float* qhw = (const float*)d_in[7];
  const float* qhb = (const float*)d_in[8];
  const float* wq = (const float*)d_in[9];
  const float* dwih = (const float*)d_in[10];
  const float* dwhh = (const float*)d_in[11];
  const float* dbih = (const float*)d_in[12];
  const float* dbhh = (const float*)d_in[13];
  const float* w1 = (const float*)d_in[14];
  const float* b1 = (const float*)d_in[15];
  const float* w2 = (const float*)d_in[16];
  const float* b2 = (const float*)d_in[17];
  float* out = (float*)d_out;

  char* ws = (char*)d_ws;
  unsigned long long* mb1 = (unsigned long long*)(ws + WSO_MB1);
  unsigned long long* hidacc = (unsigned long long*)(ws + WSO_HIDACC);
  unsigned long long* qacc = (unsigned long long*)(ws + WSO_QACC);
  float* gi_fix = (float*)(ws + WSO_GIFIX);
  float* hid_fix = (float*)(ws + WSO_HIDFIX);
  float* qhwT = (float*)(ws + WSO_QHWT);
  float* w2T = (float*)(ws + WSO_W2T);
  float* dava = (float*)(ws + WSO_DAVA);
  float* dec_hist = (float*)(ws + WSO_DECH);
  float* feat = (float*)(ws + WSO_FEAT);
  float* sbuf = (float*)(ws + WSO_SBUF);

  // zero mailbox + reduce accumulators — required every launch
  hipMemsetAsync(ws, 0, WSO_ZEND, stream);

  transpose_k<<<896, 256, 0, stream>>>(qhw, w2, qhwT, w2T);
  gemm64<<<dim3(32, 12), 256, 0, stream>>>(x_fix, 64, qwih, 1088, 0, qbih,
                                           gi_fix, 768, 64);
  gemm64<<<dim3(32, 4), 256, 0, stream>>>(x_fix, 64, qhw, 832, 256, qhb,
                                          hid_fix, 256, 64);

  seq_kernel<<<NBLK, NTH, 0, stream>>>(x_fix, x_att, qwih, qwhh, qbhh,
                                       qhwT, wq, dwih, dwhh, dbih, dbhh,
                                       gi_fix, hid_fix, mb1, hidacc, qacc,
                                       dava, dec_hist, out);

  featcopy<<<2048, 256, 0, stream>>>(dec_hist, x_fix, dava, feat);
  gemm64<<<dim3(32, 4), 256, 0, stream>>>(feat, 832, w1, 896, 0, b1,
                                          sbuf, 256, 832);
  final_k<<<2048, 256, 0, stream>>>(x_att, sbuf, w1, w2T, b2, out);
}